// Round 8
// baseline (481.701 us; speedup 1.0000x reference)
//
#include <hip/hip_runtime.h>
#include <math.h>

// Problem constants
#define BATCH 16
#define CH    256
#define CRR   16      // reduced channels
#define HWSZ  16384   // 128*128
#define NPLANES (BATCH * CH)   // 4096

// native vector type (ext_vector) — accepted by __builtin_nontemporal_*
typedef float vfloat4 __attribute__((ext_vector_type(4)));

// ---------------------------------------------------------------------------
// Kernel 1: global average pool. One block per (b,c) plane (4096 blocks).
// Forward order 0..4095. Allocating loads: x ends the pass L3-resident,
// most-recent = highest plane index.
// ---------------------------------------------------------------------------
__global__ __launch_bounds__(256) void pool_kernel(const float* __restrict__ x,
                                                   float* __restrict__ pooled) {
    const int bc = blockIdx.x;
    const int t  = threadIdx.x;
    const vfloat4* plane = reinterpret_cast<const vfloat4*>(x + (size_t)bc * HWSZ);

    float sum = 0.0f;
#pragma unroll
    for (int k = 0; k < 16; ++k) {
        vfloat4 v = plane[k * 256 + t];
        sum += (v.x + v.y) + (v.z + v.w);
    }

    // wave (64-lane) reduction
#pragma unroll
    for (int off = 32; off > 0; off >>= 1)
        sum += __shfl_down(sum, off, 64);

    __shared__ float part[4];
    const int lane = t & 63;
    const int wid  = t >> 6;
    if (lane == 0) part[wid] = sum;
    __syncthreads();
    if (t == 0) {
        float tot = (part[0] + part[1]) + (part[2] + part[3]);
        pooled[bc] = tot * (1.0f / 16384.0f);
    }
}

// ---------------------------------------------------------------------------
// Kernel 2: fc (recomputed per block, trivial) + scale.
// REVERSE plane order (4095..0): read most-recently-cached planes first so
// the pool pass's L3 residency is consumed before LRU eviction reaches it.
// out stores NON-TEMPORAL: no allocation -> nothing evicts x during scale.
// ---------------------------------------------------------------------------
__global__ __launch_bounds__(256) void scale_kernel(const float* __restrict__ x,
                                                    const float* __restrict__ pooled,
                                                    const float* __restrict__ w1,  // [CRR][CH]
                                                    const float* __restrict__ b1,  // [CRR]
                                                    const float* __restrict__ w2,  // [CH][CRR]
                                                    const float* __restrict__ b2,  // [CH]
                                                    float* __restrict__ out) {
    const int bc = (NPLANES - 1) - blockIdx.x;   // reverse traversal
    const int t  = threadIdx.x;
    const int b  = bc >> 8;         // batch
    const int c  = bc & 255;        // channel

    __shared__ float p_lds[CH];
    __shared__ float h_lds[CRR];

    p_lds[t] = pooled[b * CH + t];
    __syncthreads();

    // h[r] = leaky( b1[r] + dot(pooled[b,:], w1[r,:]) )
    {
        const int r   = t >> 4;     // 0..15
        const int seg = t & 15;     // position within 16-lane segment
        const float* wrow = w1 + r * CH + seg * 16;
        const float* pp   = p_lds + seg * 16;
        float ps = 0.0f;
#pragma unroll
        for (int j = 0; j < 16; ++j)
            ps += pp[j] * wrow[j];
#pragma unroll
        for (int m = 8; m > 0; m >>= 1)
            ps += __shfl_xor(ps, m, 64);
        if (seg == 0) {
            float h = ps + b1[r];
            h_lds[r] = (h >= 0.0f) ? h : 0.01f * h;
        }
    }
    __syncthreads();

    // every thread redundantly computes this plane's gate (16 FMA + exp)
    float z = b2[c];
    {
        const float* wcol = w2 + c * CRR;
#pragma unroll
        for (int r = 0; r < CRR; ++r)
            z += h_lds[r] * wcol[r];
    }
    const float sc = 1.0f / (1.0f + expf(-z));

    // stream the plane; non-temporal stores (no cache allocation)
    const vfloat4* xin = reinterpret_cast<const vfloat4*>(x + (size_t)bc * HWSZ);
    vfloat4*       o   = reinterpret_cast<vfloat4*>(out + (size_t)bc * HWSZ);
#pragma unroll
    for (int k = 0; k < 16; ++k) {
        vfloat4 v = xin[k * 256 + t];
        v *= sc;
        __builtin_nontemporal_store(v, &o[k * 256 + t]);
    }
}

extern "C" void kernel_launch(void* const* d_in, const int* in_sizes, int n_in,
                              void* d_out, int out_size, void* d_ws, size_t ws_size,
                              hipStream_t stream) {
    const float* x  = (const float*)d_in[0];   // [16,256,128,128]
    const float* w1 = (const float*)d_in[1];   // [16,256]
    const float* b1 = (const float*)d_in[2];   // [16]
    const float* w2 = (const float*)d_in[3];   // [256,16]
    const float* b2 = (const float*)d_in[4];   // [256]
    float* out    = (float*)d_out;
    float* pooled = (float*)d_ws;              // 4096 floats

    pool_kernel<<<NPLANES, 256, 0, stream>>>(x, pooled);
    scale_kernel<<<NPLANES, 256, 0, stream>>>(x, pooled, w1, b1, w2, b2, out);
}